// Round 7
// baseline (525.126 us; speedup 1.0000x reference)
//
#include <hip/hip_runtime.h>

#define N_NODES 512
#define FDIM    3072
#define HEADS   4
#define HFD     12288        // HEADS*FDIM
#define E_IN    4096
#define E_TOT   4608         // E_IN + N self loops
#define EPSV    1e-5f
#define SLOPE   0.2f
#define LCAP    256          // per-dst edge cache (max observed deg ~25)

typedef unsigned short u16;
typedef unsigned int   u32;

typedef short s16x8 __attribute__((ext_vector_type(8)));
typedef float f32x4 __attribute__((ext_vector_type(4)));

__device__ __forceinline__ u16 f2bf(float f){
  u32 u = __builtin_bit_cast(u32, f);
  u = (u + 0x7fffu + ((u >> 16) & 1u)) >> 16;
  return (u16)u;
}
__device__ __forceinline__ float bf2f(u16 h){
  return __builtin_bit_cast(float, ((u32)h) << 16);
}
__device__ __forceinline__ float bflo(u32 p){
  return __builtin_bit_cast(float, p << 16);
}
__device__ __forceinline__ float bfhi(u32 p){
  return __builtin_bit_cast(float, p & 0xffff0000u);
}

// async global -> LDS, 16 bytes per lane, dest = wave-uniform base + lane*16
__device__ __forceinline__ void gl_lds16(const u16* g, u16* l){
  __builtin_amdgcn_global_load_lds(
      (const __attribute__((address_space(1))) unsigned int*)g,
      (__attribute__((address_space(3))) unsigned int*)l, 16, 0, 0);
}

// ---------------- CSR build from ei alone: count + scan + scatter ----------
__global__ void k_csr(const int* __restrict__ ei, int* __restrict__ cnt,
                      int* __restrict__ off, int* __restrict__ elist){
  __shared__ int s[512];
  __shared__ int cur[512];
  int t = threadIdx.x;
  s[t] = 0;
  __syncthreads();
  for (int e = t; e < E_TOT; e += 512){
    int d = (e < E_IN) ? ei[E_IN + e] : (e - E_IN);
    atomicAdd(&s[d], 1);
  }
  __syncthreads();
  int v = s[t];
  cnt[t] = v;
  for (int dd = 1; dd < 512; dd <<= 1){
    int add = (t >= dd) ? s[t - dd] : 0;
    __syncthreads();
    s[t] += add;
    __syncthreads();
  }
  int exc = s[t] - v;
  off[t] = exc;
  cur[t] = exc;
  __syncthreads();
  for (int e = t; e < E_TOT; e += 512){
    int d = (e < E_IN) ? ei[E_IN + e] : (e - E_IN);
    int pos = atomicAdd(&cur[d], 1);
    elist[pos] = e;
  }
}

// ---------------- fc1 (1x1 conv C=3) + BN1 -> hf bf16 [512][3072] ----------
__global__ void k_fc1(const float* __restrict__ x, const float* __restrict__ W,
                      const float* __restrict__ b, const float* __restrict__ g,
                      const float* __restrict__ bb, const float* __restrict__ m,
                      const float* __restrict__ v, u16* __restrict__ hf){
  int id = blockIdx.x * 256 + threadIdx.x;   // 0..524287
  int n = id >> 10, p = id & 1023;
  float x0 = x[n * FDIM + p];
  float x1 = x[n * FDIM + 1024 + p];
  float x2 = x[n * FDIM + 2048 + p];
#pragma unroll
  for (int c = 0; c < 3; ++c){
    float t = b[c] + W[c*3+0]*x0 + W[c*3+1]*x1 + W[c*3+2]*x2;
    float inv = g[c] * rsqrtf(v[c] + EPSV);
    float o = t * inv + (bb[c] - m[c] * inv);
    hf[n * FDIM + c * 1024 + p] = f2bf(o);
  }
}

// ---------------- big GEMM: hf[512x3072] @ [Wl|Wr][3072x24576] + bias ------
// M-split x2: BM=256, BN=64, BK=32 -> 768 blocks = 3/CU for TLP latency hiding.
// Same-N pairs placed 8 ids apart -> same XCD -> B weight stream shared via L2.
// A via async global_load_lds (XOR-swizzled, double-buffered), B reg-prefetched
// fp32 -> bf16 into double-buffered LDS. ONE barrier per K-step.
// NOTE (R0-R4 evidence): this exact structure measured 193.5us; counted-vmcnt
// variants (R1/R3), 2x occupancy (R2), and A-direct-load (R4) all regressed.
// Per-step time is invariant under drain policy / occupancy / LDS traffic --
// do not re-attempt schedule surgery on this skeleton.
__global__ __launch_bounds__(256, 3) void k_gemm(
    const u16* __restrict__ hf, const float* __restrict__ Wl,
    const float* __restrict__ bl, const float* __restrict__ Wr,
    const float* __restrict__ br, u16* __restrict__ xl, u16* __restrict__ xr){
  __shared__ u16 As[2][256 * 32];   // 16 KB per buf
  __shared__ u16 Bs[2][64 * 40];    // 5 KB per buf (pad 40)

  const int tid  = threadIdx.x;
  const int wave = tid >> 6, lane = tid & 63;
  const int quad = lane >> 4, l16 = lane & 15;

  const int g = blockIdx.x;
  const int ntile = (g >> 4) * 8 + (g & 7);   // 0..383
  const int mhalf = (g >> 3) & 1;             // pair (mhalf=0,1) is 8 ids apart
  const int n0 = ntile * 64;
  const int rbase = mhalf * 256;

  const float* Wg; const float* biasp; u16* outp; int cb;
  if (n0 < HFD){ Wg = Wl; biasp = bl; outp = xl; cb = n0; }
  else         { Wg = Wr; biasp = br; outp = xr; cb = n0 - HFD; }

  // A DMA source: instr i of wave w covers rows rbase + w*64 + i*16 .. +15.
  // lane L: row += (L>>2), stores logical chunk (L&3)^((L>>3)&3) at pos L&3.
  const u16* ga = hf + (size_t)(rbase + wave * 64 + (lane >> 2)) * FDIM
                     + (((lane & 3) ^ ((lane >> 3) & 3)) << 3);

  // B staging: thread -> (col bn, k-octet bkh), 8 fp32 each
  const int bn = tid & 63, bkh = tid >> 6;
  const float* gb = Wg + (size_t)bkh * 8 * HFD + (cb + bn);
  const int bwo = bn * 40 + bkh * 8;

  // fragment read offsets (u16 units)
  const int araw = (wave * 64 + l16) * 32 + ((quad ^ ((l16 >> 1) & 3)) << 3);
  const int brd  = l16 * 40 + quad * 8;

  f32x4 acc[4][4];
#pragma unroll
  for (int i = 0; i < 4; ++i)
#pragma unroll
    for (int j = 0; j < 4; ++j) acc[i][j] = (f32x4){0.f, 0.f, 0.f, 0.f};

  float bv[8];
#pragma unroll
  for (int j = 0; j < 8; ++j) bv[j] = gb[(size_t)j * HFD];
#pragma unroll
  for (int i = 0; i < 4; ++i)
    gl_lds16(ga + (size_t)i * 16 * FDIM, As[0] + (wave * 4 + i) * 512);
  {
    u32 p0 = (u32)f2bf(bv[0]) | ((u32)f2bf(bv[1]) << 16);
    u32 p1 = (u32)f2bf(bv[2]) | ((u32)f2bf(bv[3]) << 16);
    u32 p2 = (u32)f2bf(bv[4]) | ((u32)f2bf(bv[5]) << 16);
    u32 p3 = (u32)f2bf(bv[6]) | ((u32)f2bf(bv[7]) << 16);
    *(uint4*)(Bs[0] + bwo) = make_uint4(p0, p1, p2, p3);
  }
#pragma unroll
  for (int j = 0; j < 8; ++j) bv[j] = gb[(size_t)(32 + j) * HFD];
  __syncthreads();

#define GEMM_BODY(KS, CUR, NXT)                                               \
  {                                                                           \
    const int ksv = (KS);                                                     \
    if (ksv < 95){                                                            \
      _Pragma("unroll")                                                       \
      for (int i = 0; i < 4; ++i)                                             \
        gl_lds16(ga + (size_t)i * 16 * FDIM + (ksv + 1) * 32,                 \
                 As[NXT] + (wave * 4 + i) * 512);                             \
      u32 p0 = (u32)f2bf(bv[0]) | ((u32)f2bf(bv[1]) << 16);                   \
      u32 p1 = (u32)f2bf(bv[2]) | ((u32)f2bf(bv[3]) << 16);                   \
      u32 p2 = (u32)f2bf(bv[4]) | ((u32)f2bf(bv[5]) << 16);                   \
      u32 p3 = (u32)f2bf(bv[6]) | ((u32)f2bf(bv[7]) << 16);                   \
      *(uint4*)(Bs[NXT] + bwo) = make_uint4(p0, p1, p2, p3);                  \
      int kn = (ksv + 2 < 96 ? ksv + 2 : 95) * 32;                            \
      _Pragma("unroll")                                                       \
      for (int j = 0; j < 8; ++j) bv[j] = gb[(size_t)(kn + j) * HFD];         \
    }                                                                         \
    s16x8 af[4], bfr[4];                                                      \
    _Pragma("unroll")                                                         \
    for (int i = 0; i < 4; ++i)                                               \
      af[i] = __builtin_bit_cast(s16x8, *(const uint4*)(As[CUR] + araw + i * 512)); \
    _Pragma("unroll")                                                         \
    for (int j = 0; j < 4; ++j)                                               \
      bfr[j] = __builtin_bit_cast(s16x8, *(const uint4*)(Bs[CUR] + brd + j * 640)); \
    _Pragma("unroll")                                                         \
    for (int i = 0; i < 4; ++i)                                               \
      _Pragma("unroll")                                                       \
      for (int j = 0; j < 4; ++j)                                             \
        acc[i][j] = __builtin_amdgcn_mfma_f32_16x16x32_bf16(af[i], bfr[j], acc[i][j], 0, 0, 0); \
    __syncthreads();                                                          \
  }

  for (int ks = 0; ks < 96; ks += 2){
    GEMM_BODY(ks, 0, 1);
    GEMM_BODY(ks + 1, 1, 0);
  }
#undef GEMM_BODY

  // epilogue: + bias, store bf16
  float bj[4];
#pragma unroll
  for (int j = 0; j < 4; ++j) bj[j] = biasp[cb + j * 16 + l16];
#pragma unroll
  for (int i = 0; i < 4; ++i){
    int mrow = rbase + wave * 64 + i * 16 + quad * 4;
#pragma unroll
    for (int r = 0; r < 4; ++r){
      u16* orow = outp + (size_t)(mrow + r) * HFD + cb + l16;
#pragma unroll
      for (int j = 0; j < 4; ++j)
        orow[j * 16] = f2bf(acc[i][j][r] + bj[j]);
    }
  }
}

// ---------------- fused GATv2 logits + segment softmax, per-dst block ------
// Block = dst node n (512 blocks, 256 thr = 4 waves, wave h <-> head h).
// xr[n] and att slices hoisted to registers ONCE; per edge only xl[s] is
// streamed (24KB). Traffic vs edge-parallel version: 442 MB -> ~150 MB and
// logits never round-trip through global. Softmax done in-block from LDS.
__global__ __launch_bounds__(256) void k_lsm(
    const int* __restrict__ ei, const int* __restrict__ cnt,
    const int* __restrict__ off, const int* __restrict__ elist,
    const u16* __restrict__ xl, const u16* __restrict__ xr,
    const float* __restrict__ att, float* __restrict__ alpha){
  __shared__ float s_log[LCAP][5];   // pad 5: conflict-light column reads
  __shared__ int   s_e[LCAP];
  const int n = blockIdx.x;
  const int t = threadIdx.x;
  const int h = t >> 6, lane = t & 63;
  const int deg = cnt[n], st = off[n];
  const int f0 = lane * 48;          // 64 lanes x 48 elems = 3072 = FDIM

  // hoist xr[n] (48 bf16 -> f32) and att (48 f32) slices for (h, f0..f0+47)
  float xrf[48], av[48];
  {
    const u16* xrp = xr + (size_t)n * HFD + h * FDIM + f0;
    const float* ap = att + h * FDIM + f0;
#pragma unroll
    for (int k = 0; k < 6; ++k){
      uint4 a = *(const uint4*)(xrp + k * 8);
      xrf[k*8+0]=bflo(a.x); xrf[k*8+1]=bfhi(a.x);
      xrf[k*8+2]=bflo(a.y); xrf[k*8+3]=bfhi(a.y);
      xrf[k*8+4]=bflo(a.z); xrf[k*8+5]=bfhi(a.z);
      xrf[k*8+6]=bflo(a.w); xrf[k*8+7]=bfhi(a.w);
      float4 w0 = *(const float4*)(ap + k * 8);
      float4 w1 = *(const float4*)(ap + k * 8 + 4);
      av[k*8+0]=w0.x; av[k*8+1]=w0.y; av[k*8+2]=w0.z; av[k*8+3]=w0.w;
      av[k*8+4]=w1.x; av[k*8+5]=w1.y; av[k*8+6]=w1.z; av[k*8+7]=w1.w;
    }
  }

  // per-edge logit for head h: wave-reduced a.LeakyReLU(xl[s]+xr[n]) dot
  auto edge_logit = [&](int s_node) -> float {
    const u16* xlp = xl + (size_t)s_node * HFD + h * FDIM + f0;
    float acc = 0.f;
#pragma unroll
    for (int k = 0; k < 6; ++k){
      uint4 a = *(const uint4*)(xlp + k * 8);
      float z;
      z = bflo(a.x) + xrf[k*8+0]; z = z > 0.f ? z : SLOPE * z; acc += z * av[k*8+0];
      z = bfhi(a.x) + xrf[k*8+1]; z = z > 0.f ? z : SLOPE * z; acc += z * av[k*8+1];
      z = bflo(a.y) + xrf[k*8+2]; z = z > 0.f ? z : SLOPE * z; acc += z * av[k*8+2];
      z = bfhi(a.y) + xrf[k*8+3]; z = z > 0.f ? z : SLOPE * z; acc += z * av[k*8+3];
      z = bflo(a.z) + xrf[k*8+4]; z = z > 0.f ? z : SLOPE * z; acc += z * av[k*8+4];
      z = bfhi(a.z) + xrf[k*8+5]; z = z > 0.f ? z : SLOPE * z; acc += z * av[k*8+5];
      z = bflo(a.w) + xrf[k*8+6]; z = z > 0.f ? z : SLOPE * z; acc += z * av[k*8+6];
      z = bfhi(a.w) + xrf[k*8+7]; z = z > 0.f ? z : SLOPE * z; acc += z * av[k*8+7];
    }
#pragma unroll
    for (int o = 32; o > 0; o >>= 1) acc += __shfl_down(acc, o);
    return acc;   // lane 0 holds the logit
  };

  if (deg <= LCAP){
    for (int jb = 0; jb < deg; ++jb){
      int e = elist[st + jb];
      if (t == 0) s_e[jb] = e;
      int s = (e < E_IN) ? ei[e] : (e - E_IN);
      float lg = edge_logit(s);
      if (lane == 0) s_log[jb][h] = lg;
    }
    __syncthreads();
    // wave h: softmax over its head's column
    float mx = -1e30f;
    for (int j = lane; j < deg; j += 64) mx = fmaxf(mx, s_log[j][h]);
#pragma unroll
    for (int o = 32; o > 0; o >>= 1) mx = fmaxf(mx, __shfl_down(mx, o));
    mx = __shfl(mx, 0);
    float sm = 0.f;
    for (int j = lane; j < deg; j += 64) sm += __expf(s_log[j][h] - mx);
#pragma unroll
    for (int o = 32; o > 0; o >>= 1) sm += __shfl_down(sm, o);
    sm = __shfl(sm, 0);
    float rs = 1.f / sm;
    for (int j = lane; j < deg; j += 64)
      alpha[s_e[j] * 4 + h] = __expf(s_log[j][h] - mx) * rs;
  } else {
    // general fallback (not taken for this input): stage logits in alpha,
    // then 3-pass softmax in place. Wave h only touches head-h slots it
    // itself wrote, so no cross-wave sync is needed.
    for (int jb = 0; jb < deg; ++jb){
      int e = elist[st + jb];
      int s = (e < E_IN) ? ei[e] : (e - E_IN);
      float lg = edge_logit(s);
      if (lane == 0) alpha[e * 4 + h] = lg;
    }
    float mx = -1e30f;
    for (int j = lane; j < deg; j += 64){
      int e = elist[st + j];
      mx = fmaxf(mx, alpha[e * 4 + h]);
    }
#pragma unroll
    for (int o = 32; o > 0; o >>= 1) mx = fmaxf(mx, __shfl_down(mx, o));
    mx = __shfl(mx, 0);
    float sm = 0.f;
    for (int j = lane; j < deg; j += 64){
      int e = elist[st + j];
      sm += __expf(alpha[e * 4 + h] - mx);
    }
#pragma unroll
    for (int o = 32; o > 0; o >>= 1) sm += __shfl_down(sm, o);
    sm = __shfl(sm, 0);
    float rs = 1.f / sm;
    for (int j = lane; j < deg; j += 64){
      int e = elist[st + j];
      alpha[e * 4 + h] = __expf(alpha[e * 4 + h] - mx) * rs;
    }
  }
}

// ---------------- fused aggregate + fc2/BN2/shortcut + FFN -----------------
// block = dst node; acc[12 channels][4 pixels] in registers; no agg buffer.
__global__ __launch_bounds__(256) void k_aggfinal(
    const int* __restrict__ ei, const int* __restrict__ cnt,
    const int* __restrict__ off, const int* __restrict__ elist,
    const float* __restrict__ alpha, const u16* __restrict__ xl,
    const float* __restrict__ gat_b,
    const float* __restrict__ W2, const float* __restrict__ b2,
    const float* __restrict__ g2, const float* __restrict__ bb2,
    const float* __restrict__ m2, const float* __restrict__ v2,
    const float* __restrict__ W3, const float* __restrict__ b3,
    const float* __restrict__ g3, const float* __restrict__ bb3,
    const float* __restrict__ m3, const float* __restrict__ v3,
    const float* __restrict__ W4, const float* __restrict__ b4,
    const float* __restrict__ g4, const float* __restrict__ bb4,
    const float* __restrict__ m4, const float* __restrict__ v4,
    const float* __restrict__ x, float* __restrict__ out){
  __shared__ int    s_src[128];
  __shared__ float4 s_al[128];
  const int n = blockIdx.x;
  const int t = threadIdx.x;
  const int p4 = t * 4;
  const int deg = cnt[n], st = off[n];

  float acc[12][4];
#pragma unroll
  for (int o = 0; o < 12; ++o)
#pragma unroll
    for (int r = 0; r < 4; ++r) acc[o][r] = 0.f;

  for (int base = 0; base < deg; base += 128){
    int cn = min(deg - base, 128);
    if (t < cn){
      int e = elist[st + base + t];
      s_src[t] = (e < E_IN) ? ei[e] : (e - E_IN);
      s_al[t] = *(const float4*)(alpha + e * 4);
    }
    __syncthreads();
    for (int j = 0; j < cn; ++j){
      int s = s_src[j];
      float4 al4 = s_al[j];
      float alh[4] = {al4.x, al4.y, al4.z, al4.w};
      const u16* bp = xl + (size_t)s * HFD;
#pragma unroll
      for (int h = 0; h < 4; ++h){
#pragma unroll
        for (int c = 0; c < 3; ++c){
          ushort4 xv = *(const ushort4*)(bp + h * FDIM + c * 1024 + p4);
          acc[h*3+c][0] += alh[h] * bf2f(xv.x);
          acc[h*3+c][1] += alh[h] * bf2f(xv.y);
          acc[h*3+c][2] += alh[h] * bf2f(xv.z);
          acc[h*3+c][3] += alh[h] * bf2f(xv.w);
        }
      }
    }
    __syncthreads();
  }

  // + gat bias
#pragma unroll
  for (int o = 0; o < 12; ++o){
    float4 gv = *(const float4*)(gat_b + o * 1024 + p4);
    acc[o][0] += gv.x; acc[o][1] += gv.y; acc[o][2] += gv.z; acc[o][3] += gv.w;
  }
  // shortcut x
  float xv[3][4];
#pragma unroll
  for (int c = 0; c < 3; ++c){
    float4 t4 = *(const float4*)(x + (size_t)n * FDIM + c * 1024 + p4);
    xv[c][0] = t4.x; xv[c][1] = t4.y; xv[c][2] = t4.z; xv[c][3] = t4.w;
  }
  float o4[3][4];
#pragma unroll
  for (int r = 0; r < 4; ++r){
    float gch[3];
#pragma unroll
    for (int c = 0; c < 3; ++c){
      float tt = b2[c];
#pragma unroll
      for (int o = 0; o < 12; ++o) tt += W2[c * 12 + o] * acc[o][r];
      float inv = g2[c] * rsqrtf(v2[c] + EPSV);
      gch[c] = tt * inv + (bb2[c] - m2[c] * inv) + xv[c][r];
    }
    float f1[3];
#pragma unroll
    for (int c = 0; c < 3; ++c){
      float tt = b3[c] + W3[c*3+0]*gch[0] + W3[c*3+1]*gch[1] + W3[c*3+2]*gch[2];
      float inv = g3[c] * rsqrtf(v3[c] + EPSV);
      float vv = tt * inv + (bb3[c] - m3[c] * inv);
      f1[c] = fmaxf(vv, 0.f);
    }
#pragma unroll
    for (int c = 0; c < 3; ++c){
      float tt = b4[c] + W4[c*3+0]*f1[0] + W4[c*3+1]*f1[1] + W4[c*3+2]*f1[2];
      float inv = g4[c] * rsqrtf(v4[c] + EPSV);
      o4[c][r] = tt * inv + (bb4[c] - m4[c] * inv) + gch[c];
    }
  }
#pragma unroll
  for (int c = 0; c < 3; ++c)
    *(float4*)(out + (size_t)n * FDIM + c * 1024 + p4) =
        make_float4(o4[c][0], o4[c][1], o4[c][2], o4[c][3]);
}

extern "C" void kernel_launch(void* const* d_in, const int* in_sizes, int n_in,
                              void* d_out, int out_size, void* d_ws, size_t ws_size,
                              hipStream_t stream){
  (void)in_sizes; (void)n_in; (void)out_size; (void)ws_size;
  const float* x     = (const float*)d_in[0];
  const int*   ei    = (const int*)d_in[1];
  const float* fc1_W = (const float*)d_in[2];
  const float* fc1_b = (const float*)d_in[3];
  const float* bn1_g = (const float*)d_in[4];
  const float* bn1_b = (const float*)d_in[5];
  const float* bn1_m = (const float*)d_in[6];
  const float* bn1_v = (const float*)d_in[7];
  const float* Wl    = (const float*)d_in[8];
  const float* bl    = (const float*)d_in[9];
  const float* Wr    = (const float*)d_in[10];
  const float* br    = (const float*)d_in[11];
  const float* att   = (const float*)d_in[12];
  const float* gat_b = (const float*)d_in[13];
  const float* fc2_W = (const float*)d_in[14];
  const float* fc2_b = (const float*)d_in[15];
  const float* bn2_g = (const float*)d_in[16];
  const float* bn2_b = (const float*)d_in[17];
  const float* bn2_m = (const float*)d_in[18];
  const float* bn2_v = (const float*)d_in[19];
  const float* ffn1_W= (const float*)d_in[20];
  const float* ffn1_b= (const float*)d_in[21];
  const float* bnf1_g= (const float*)d_in[22];
  const float* bnf1_b= (const float*)d_in[23];
  const float* bnf1_m= (const float*)d_in[24];
  const float* bnf1_v= (const float*)d_in[25];
  const float* ffn2_W= (const float*)d_in[26];
  const float* ffn2_b= (const float*)d_in[27];
  const float* bnf2_g= (const float*)d_in[28];
  const float* bnf2_b= (const float*)d_in[29];
  const float* bnf2_m= (const float*)d_in[30];
  const float* bnf2_v= (const float*)d_in[31];

  char* w = (char*)d_ws;
  u16*   hf     = (u16*)(w);                    // 3,145,728
  u16*   xl     = (u16*)(w + 3145728);          // 12,582,912
  u16*   xr     = (u16*)(w + 15728640);         // 12,582,912
  float* alpha  = (float*)(w + 28385280);       // 73,728
  int*   cnt    = (int*)(w + 28459008);         // 2048
  int*   offp   = (int*)(w + 28461056);         // 2048
  int*   elist  = (int*)(w + 28465152);         // 18,432

  k_csr<<<1, 512, 0, stream>>>(ei, cnt, offp, elist);
  k_fc1<<<2048, 256, 0, stream>>>(x, fc1_W, fc1_b, bn1_g, bn1_b, bn1_m, bn1_v, hf);
  k_gemm<<<768, 256, 0, stream>>>(hf, Wl, bl, Wr, br, xl, xr);
  k_lsm<<<512, 256, 0, stream>>>(ei, cnt, offp, elist, xl, xr, att, alpha);
  k_aggfinal<<<512, 256, 0, stream>>>(ei, cnt, offp, elist, alpha, xl, gat_b,
                                      fc2_W, fc2_b, bn2_g, bn2_b, bn2_m, bn2_v,
                                      ffn1_W, ffn1_b, bnf1_g, bnf1_b, bnf1_m, bnf1_v,
                                      ffn2_W, ffn2_b, bnf2_g, bnf2_b, bnf2_m, bnf2_v,
                                      x, (float*)d_out);
}

// Round 8
// 523.901 us; speedup vs baseline: 1.0023x; 1.0023x over previous
//
#include <hip/hip_runtime.h>

#define N_NODES 512
#define FDIM    3072
#define HEADS   4
#define HFD     12288        // HEADS*FDIM
#define E_IN    4096
#define E_TOT   4608         // E_IN + N self loops
#define EPSV    1e-5f
#define SLOPE   0.2f
#define LCAP    128          // per-dst in-LDS edge cache (max observed deg ~25)

typedef unsigned short u16;
typedef unsigned int   u32;

typedef short s16x8 __attribute__((ext_vector_type(8)));
typedef float f32x4 __attribute__((ext_vector_type(4)));

__device__ __forceinline__ u16 f2bf(float f){
  u32 u = __builtin_bit_cast(u32, f);
  u = (u + 0x7fffu + ((u >> 16) & 1u)) >> 16;
  return (u16)u;
}
__device__ __forceinline__ float bf2f(u16 h){
  return __builtin_bit_cast(float, ((u32)h) << 16);
}
__device__ __forceinline__ float bflo(u32 p){
  return __builtin_bit_cast(float, p << 16);
}
__device__ __forceinline__ float bfhi(u32 p){
  return __builtin_bit_cast(float, p & 0xffff0000u);
}

// async global -> LDS, 16 bytes per lane, dest = wave-uniform base + lane*16
__device__ __forceinline__ void gl_lds16(const u16* g, u16* l){
  __builtin_amdgcn_global_load_lds(
      (const __attribute__((address_space(1))) unsigned int*)g,
      (__attribute__((address_space(3))) unsigned int*)l, 16, 0, 0);
}

// ---------------- k_pre: fc1 (blocks 0..2047) || CSR build (block 2048) ----
// fc1 and CSR are independent -> merged into one launch, no sync needed.
__global__ __launch_bounds__(256) void k_pre(
    const float* __restrict__ x, const float* __restrict__ W,
    const float* __restrict__ b, const float* __restrict__ g,
    const float* __restrict__ bb, const float* __restrict__ m,
    const float* __restrict__ v, u16* __restrict__ hf,
    const int* __restrict__ ei, int* __restrict__ cnt,
    int* __restrict__ off, int* __restrict__ elist){
  if (blockIdx.x < 2048){
    int id = blockIdx.x * 256 + threadIdx.x;   // 0..524287
    int n = id >> 10, p = id & 1023;
    float x0 = x[n * FDIM + p];
    float x1 = x[n * FDIM + 1024 + p];
    float x2 = x[n * FDIM + 2048 + p];
#pragma unroll
    for (int c = 0; c < 3; ++c){
      float t = b[c] + W[c*3+0]*x0 + W[c*3+1]*x1 + W[c*3+2]*x2;
      float inv = g[c] * rsqrtf(v[c] + EPSV);
      float o = t * inv + (bb[c] - m[c] * inv);
      hf[n * FDIM + c * 1024 + p] = f2bf(o);
    }
  } else {
    // CSR: count + 512-wide inclusive scan (ping-pong, 2 slots/thread) + scatter
    __shared__ int sa[512], sb[512];
    int t = threadIdx.x;
    sa[t] = 0; sa[t + 256] = 0;
    __syncthreads();
    for (int e = t; e < E_TOT; e += 256){
      int d = (e < E_IN) ? ei[E_IN + e] : (e - E_IN);
      atomicAdd(&sa[d], 1);
    }
    __syncthreads();
    int c0 = sa[t], c1 = sa[t + 256];
    cnt[t] = c0; cnt[t + 256] = c1;
    int* src = sa; int* dst = sb;
    for (int d = 1; d < 512; d <<= 1){
      dst[t] = src[t] + (t >= d ? src[t - d] : 0);
      int i2 = t + 256;
      dst[i2] = src[i2] + (i2 >= d ? src[i2 - d] : 0);
      __syncthreads();
      int* tmp = src; src = dst; dst = tmp;
    }
    off[t] = src[t] - c0; off[t + 256] = src[t + 256] - c1;
    dst[t] = src[t] - c0; dst[t + 256] = src[t + 256] - c1;   // dst = cursor
    __syncthreads();
    for (int e = t; e < E_TOT; e += 256){
      int d = (e < E_IN) ? ei[E_IN + e] : (e - E_IN);
      int pos = atomicAdd(&dst[d], 1);
      elist[pos] = e;
    }
  }
}

// ---------------- big GEMM: hf[512x3072] @ [Wl|Wr][3072x24576] + bias ------
// M-split x2: BM=256, BN=64, BK=32 -> 768 blocks = 3/CU for TLP latency hiding.
// Same-N pairs placed 8 ids apart -> same XCD -> B weight stream shared via L2.
// A via async global_load_lds (XOR-swizzled, double-buffered), B reg-prefetched
// fp32 -> bf16 into double-buffered LDS. ONE barrier per K-step.
// NOTE (R0-R4 evidence): this exact structure measured 193.5us; counted-vmcnt
// variants (R1/R3), 2x occupancy (R2), and A-direct-load (R4) all regressed.
// Per-step time is invariant under drain policy / occupancy / LDS traffic --
// do not re-attempt schedule surgery on this skeleton.
__global__ __launch_bounds__(256, 3) void k_gemm(
    const u16* __restrict__ hf, const float* __restrict__ Wl,
    const float* __restrict__ bl, const float* __restrict__ Wr,
    const float* __restrict__ br, u16* __restrict__ xl, u16* __restrict__ xr){
  __shared__ u16 As[2][256 * 32];   // 16 KB per buf
  __shared__ u16 Bs[2][64 * 40];    // 5 KB per buf (pad 40)

  const int tid  = threadIdx.x;
  const int wave = tid >> 6, lane = tid & 63;
  const int quad = lane >> 4, l16 = lane & 15;

  const int g = blockIdx.x;
  const int ntile = (g >> 4) * 8 + (g & 7);   // 0..383
  const int mhalf = (g >> 3) & 1;             // pair (mhalf=0,1) is 8 ids apart
  const int n0 = ntile * 64;
  const int rbase = mhalf * 256;

  const float* Wg; const float* biasp; u16* outp; int cb;
  if (n0 < HFD){ Wg = Wl; biasp = bl; outp = xl; cb = n0; }
  else         { Wg = Wr; biasp = br; outp = xr; cb = n0 - HFD; }

  // A DMA source: instr i of wave w covers rows rbase + w*64 + i*16 .. +15.
  // lane L: row += (L>>2), stores logical chunk (L&3)^((L>>3)&3) at pos L&3.
  const u16* ga = hf + (size_t)(rbase + wave * 64 + (lane >> 2)) * FDIM
                     + (((lane & 3) ^ ((lane >> 3) & 3)) << 3);

  // B staging: thread -> (col bn, k-octet bkh), 8 fp32 each
  const int bn = tid & 63, bkh = tid >> 6;
  const float* gb = Wg + (size_t)bkh * 8 * HFD + (cb + bn);
  const int bwo = bn * 40 + bkh * 8;

  // fragment read offsets (u16 units)
  const int araw = (wave * 64 + l16) * 32 + ((quad ^ ((l16 >> 1) & 3)) << 3);
  const int brd  = l16 * 40 + quad * 8;

  f32x4 acc[4][4];
#pragma unroll
  for (int i = 0; i < 4; ++i)
#pragma unroll
    for (int j = 0; j < 4; ++j) acc[i][j] = (f32x4){0.f, 0.f, 0.f, 0.f};

  float bv[8];
#pragma unroll
  for (int j = 0; j < 8; ++j) bv[j] = gb[(size_t)j * HFD];
#pragma unroll
  for (int i = 0; i < 4; ++i)
    gl_lds16(ga + (size_t)i * 16 * FDIM, As[0] + (wave * 4 + i) * 512);
  {
    u32 p0 = (u32)f2bf(bv[0]) | ((u32)f2bf(bv[1]) << 16);
    u32 p1 = (u32)f2bf(bv[2]) | ((u32)f2bf(bv[3]) << 16);
    u32 p2 = (u32)f2bf(bv[4]) | ((u32)f2bf(bv[5]) << 16);
    u32 p3 = (u32)f2bf(bv[6]) | ((u32)f2bf(bv[7]) << 16);
    *(uint4*)(Bs[0] + bwo) = make_uint4(p0, p1, p2, p3);
  }
#pragma unroll
  for (int j = 0; j < 8; ++j) bv[j] = gb[(size_t)(32 + j) * HFD];
  __syncthreads();

#define GEMM_BODY(KS, CUR, NXT)                                               \
  {                                                                           \
    const int ksv = (KS);                                                     \
    if (ksv < 95){                                                            \
      _Pragma("unroll")                                                       \
      for (int i = 0; i < 4; ++i)                                             \
        gl_lds16(ga + (size_t)i * 16 * FDIM + (ksv + 1) * 32,                 \
                 As[NXT] + (wave * 4 + i) * 512);                             \
      u32 p0 = (u32)f2bf(bv[0]) | ((u32)f2bf(bv[1]) << 16);                   \
      u32 p1 = (u32)f2bf(bv[2]) | ((u32)f2bf(bv[3]) << 16);                   \
      u32 p2 = (u32)f2bf(bv[4]) | ((u32)f2bf(bv[5]) << 16);                   \
      u32 p3 = (u32)f2bf(bv[6]) | ((u32)f2bf(bv[7]) << 16);                   \
      *(uint4*)(Bs[NXT] + bwo) = make_uint4(p0, p1, p2, p3);                  \
      int kn = (ksv + 2 < 96 ? ksv + 2 : 95) * 32;                            \
      _Pragma("unroll")                                                       \
      for (int j = 0; j < 8; ++j) bv[j] = gb[(size_t)(kn + j) * HFD];         \
    }                                                                         \
    s16x8 af[4], bfr[4];                                                      \
    _Pragma("unroll")                                                         \
    for (int i = 0; i < 4; ++i)                                               \
      af[i] = __builtin_bit_cast(s16x8, *(const uint4*)(As[CUR] + araw + i * 512)); \
    _Pragma("unroll")                                                         \
    for (int j = 0; j < 4; ++j)                                               \
      bfr[j] = __builtin_bit_cast(s16x8, *(const uint4*)(Bs[CUR] + brd + j * 640)); \
    _Pragma("unroll")                                                         \
    for (int i = 0; i < 4; ++i)                                               \
      _Pragma("unroll")                                                       \
      for (int j = 0; j < 4; ++j)                                             \
        acc[i][j] = __builtin_amdgcn_mfma_f32_16x16x32_bf16(af[i], bfr[j], acc[i][j], 0, 0, 0); \
    __syncthreads();                                                          \
  }

  for (int ks = 0; ks < 96; ks += 2){
    GEMM_BODY(ks, 0, 1);
    GEMM_BODY(ks + 1, 1, 0);
  }
#undef GEMM_BODY

  // epilogue: + bias, store bf16
  float bj[4];
#pragma unroll
  for (int j = 0; j < 4; ++j) bj[j] = biasp[cb + j * 16 + l16];
#pragma unroll
  for (int i = 0; i < 4; ++i){
    int mrow = rbase + wave * 64 + i * 16 + quad * 4;
#pragma unroll
    for (int r = 0; r < 4; ++r){
      u16* orow = outp + (size_t)(mrow + r) * HFD + cb + l16;
#pragma unroll
      for (int j = 0; j < 4; ++j)
        orow[j * 16] = f2bf(acc[i][j][r] + bj[j]);
    }
  }
}

// ---------------- k_post: logits + softmax + aggregate + fc2/BN2 + FFN -----
// Block = dst node n (512 blocks, 4 waves, wave h <-> head h). Alpha never
// touches global memory in the common (deg <= 128) path: logits -> LDS,
// softmax -> LDS, aggregation reads LDS. Global-alpha fallback for deg > 128.
__global__ __launch_bounds__(256) void k_post(
    const int* __restrict__ ei, const int* __restrict__ cnt,
    const int* __restrict__ off, const int* __restrict__ elist,
    const u16* __restrict__ xl, const u16* __restrict__ xr,
    const float* __restrict__ att, float* __restrict__ alpha,
    const float* __restrict__ gat_b,
    const float* __restrict__ W2, const float* __restrict__ b2,
    const float* __restrict__ g2, const float* __restrict__ bb2,
    const float* __restrict__ m2, const float* __restrict__ v2,
    const float* __restrict__ W3, const float* __restrict__ b3,
    const float* __restrict__ g3, const float* __restrict__ bb3,
    const float* __restrict__ m3, const float* __restrict__ v3,
    const float* __restrict__ W4, const float* __restrict__ b4,
    const float* __restrict__ g4, const float* __restrict__ bb4,
    const float* __restrict__ m4, const float* __restrict__ v4,
    const float* __restrict__ x, float* __restrict__ out){
  __shared__ float s_log[LCAP][5];                  // pad 5: stride-5 banks
  __shared__ __align__(16) float s_alf[LCAP][4];    // alpha (also fallback stage)
  __shared__ int s_src[LCAP];
  const int n = blockIdx.x;
  const int t = threadIdx.x;
  const int h = t >> 6, lane = t & 63;
  const int deg = cnt[n], st = off[n];
  const int f0 = lane * 48;          // 64 lanes x 48 elems = 3072 = FDIM

  // hoist xr[n] (48 bf16 -> f32) and att (48 f32) slices for (h, f0..f0+47)
  float xrf[48], av[48];
  {
    const u16* xrp = xr + (size_t)n * HFD + h * FDIM + f0;
    const float* ap = att + h * FDIM + f0;
#pragma unroll
    for (int k = 0; k < 6; ++k){
      uint4 a = *(const uint4*)(xrp + k * 8);
      xrf[k*8+0]=bflo(a.x); xrf[k*8+1]=bfhi(a.x);
      xrf[k*8+2]=bflo(a.y); xrf[k*8+3]=bfhi(a.y);
      xrf[k*8+4]=bflo(a.z); xrf[k*8+5]=bfhi(a.z);
      xrf[k*8+6]=bflo(a.w); xrf[k*8+7]=bfhi(a.w);
      float4 w0 = *(const float4*)(ap + k * 8);
      float4 w1 = *(const float4*)(ap + k * 8 + 4);
      av[k*8+0]=w0.x; av[k*8+1]=w0.y; av[k*8+2]=w0.z; av[k*8+3]=w0.w;
      av[k*8+4]=w1.x; av[k*8+5]=w1.y; av[k*8+6]=w1.z; av[k*8+7]=w1.w;
    }
  }

  // per-edge logit for head h: wave-reduced a.LeakyReLU(xl[s]+xr[n]) dot
  auto edge_logit = [&](int s_node) -> float {
    const u16* xlp = xl + (size_t)s_node * HFD + h * FDIM + f0;
    float acc = 0.f;
#pragma unroll
    for (int k = 0; k < 6; ++k){
      uint4 a = *(const uint4*)(xlp + k * 8);
      float z;
      z = bflo(a.x) + xrf[k*8+0]; z = z > 0.f ? z : SLOPE * z; acc += z * av[k*8+0];
      z = bfhi(a.x) + xrf[k*8+1]; z = z > 0.f ? z : SLOPE * z; acc += z * av[k*8+1];
      z = bflo(a.y) + xrf[k*8+2]; z = z > 0.f ? z : SLOPE * z; acc += z * av[k*8+2];
      z = bfhi(a.y) + xrf[k*8+3]; z = z > 0.f ? z : SLOPE * z; acc += z * av[k*8+3];
      z = bflo(a.z) + xrf[k*8+4]; z = z > 0.f ? z : SLOPE * z; acc += z * av[k*8+4];
      z = bfhi(a.z) + xrf[k*8+5]; z = z > 0.f ? z : SLOPE * z; acc += z * av[k*8+5];
      z = bflo(a.w) + xrf[k*8+6]; z = z > 0.f ? z : SLOPE * z; acc += z * av[k*8+6];
      z = bfhi(a.w) + xrf[k*8+7]; z = z > 0.f ? z : SLOPE * z; acc += z * av[k*8+7];
    }
#pragma unroll
    for (int o = 32; o > 0; o >>= 1) acc += __shfl_down(acc, o);
    return acc;   // lane 0 holds the logit
  };

  const bool small = (deg <= LCAP);   // block-uniform branch
  if (small){
    for (int jb = 0; jb < deg; ++jb){
      int e = elist[st + jb];
      int s = (e < E_IN) ? ei[e] : (e - E_IN);
      if (t == 0) s_src[jb] = s;
      float lg = edge_logit(s);
      if (lane == 0) s_log[jb][h] = lg;
    }
    __syncthreads();
    // wave h: softmax over its head's column -> s_alf
    float mx = -1e30f;
    for (int j = lane; j < deg; j += 64) mx = fmaxf(mx, s_log[j][h]);
#pragma unroll
    for (int o = 32; o > 0; o >>= 1) mx = fmaxf(mx, __shfl_down(mx, o));
    mx = __shfl(mx, 0);
    float sm = 0.f;
    for (int j = lane; j < deg; j += 64) sm += __expf(s_log[j][h] - mx);
#pragma unroll
    for (int o = 32; o > 0; o >>= 1) sm += __shfl_down(sm, o);
    sm = __shfl(sm, 0);
    float rs = 1.f / sm;
    for (int j = lane; j < deg; j += 64)
      s_alf[j][h] = __expf(s_log[j][h] - mx) * rs;
    __syncthreads();
  } else {
    // fallback (not taken for this input): logits + softmax via global alpha.
    for (int jb = 0; jb < deg; ++jb){
      int e = elist[st + jb];
      int s = (e < E_IN) ? ei[e] : (e - E_IN);
      float lg = edge_logit(s);
      if (lane == 0) alpha[e * 4 + h] = lg;
    }
    __syncthreads();
    float mx = -1e30f;
    for (int j = lane; j < deg; j += 64){
      int e = elist[st + j];
      mx = fmaxf(mx, alpha[e * 4 + h]);
    }
#pragma unroll
    for (int o = 32; o > 0; o >>= 1) mx = fmaxf(mx, __shfl_down(mx, o));
    mx = __shfl(mx, 0);
    float sm = 0.f;
    for (int j = lane; j < deg; j += 64){
      int e = elist[st + j];
      sm += __expf(alpha[e * 4 + h] - mx);
    }
#pragma unroll
    for (int o = 32; o > 0; o >>= 1) sm += __shfl_down(sm, o);
    sm = __shfl(sm, 0);
    float rs = 1.f / sm;
    for (int j = lane; j < deg; j += 64){
      int e = elist[st + j];
      alpha[e * 4 + h] = __expf(alpha[e * 4 + h] - mx) * rs;
    }
    __syncthreads();
  }

  // ---- aggregation: acc[12 channels][4 pixels] in registers ----
  const int p4 = t * 4;
  float acc[12][4];
#pragma unroll
  for (int o = 0; o < 12; ++o)
#pragma unroll
    for (int r = 0; r < 4; ++r) acc[o][r] = 0.f;

  if (small){
    for (int j = 0; j < deg; ++j){
      int s = s_src[j];
      float alh[4] = {s_alf[j][0], s_alf[j][1], s_alf[j][2], s_alf[j][3]};
      const u16* bp = xl + (size_t)s * HFD;
#pragma unroll
      for (int hh = 0; hh < 4; ++hh){
#pragma unroll
        for (int c = 0; c < 3; ++c){
          ushort4 xv = *(const ushort4*)(bp + hh * FDIM + c * 1024 + p4);
          acc[hh*3+c][0] += alh[hh] * bf2f(xv.x);
          acc[hh*3+c][1] += alh[hh] * bf2f(xv.y);
          acc[hh*3+c][2] += alh[hh] * bf2f(xv.z);
          acc[hh*3+c][3] += alh[hh] * bf2f(xv.w);
        }
      }
    }
  } else {
    for (int base = 0; base < deg; base += LCAP){
      int cn = min(deg - base, LCAP);
      if (t < cn){
        int e = elist[st + base + t];
        s_src[t] = (e < E_IN) ? ei[e] : (e - E_IN);
        *(float4*)&s_alf[t][0] = *(const float4*)(alpha + e * 4);
      }
      __syncthreads();
      for (int j = 0; j < cn; ++j){
        int s = s_src[j];
        float alh[4] = {s_alf[j][0], s_alf[j][1], s_alf[j][2], s_alf[j][3]};
        const u16* bp = xl + (size_t)s * HFD;
#pragma unroll
        for (int hh = 0; hh < 4; ++hh){
#pragma unroll
          for (int c = 0; c < 3; ++c){
            ushort4 xv = *(const ushort4*)(bp + hh * FDIM + c * 1024 + p4);
            acc[hh*3+c][0] += alh[hh] * bf2f(xv.x);
            acc[hh*3+c][1] += alh[hh] * bf2f(xv.y);
            acc[hh*3+c][2] += alh[hh] * bf2f(xv.z);
            acc[hh*3+c][3] += alh[hh] * bf2f(xv.w);
          }
        }
      }
      __syncthreads();
    }
  }

  // + gat bias
#pragma unroll
  for (int o = 0; o < 12; ++o){
    float4 gv = *(const float4*)(gat_b + o * 1024 + p4);
    acc[o][0] += gv.x; acc[o][1] += gv.y; acc[o][2] += gv.z; acc[o][3] += gv.w;
  }
  // shortcut x
  float xv[3][4];
#pragma unroll
  for (int c = 0; c < 3; ++c){
    float4 t4 = *(const float4*)(x + (size_t)n * FDIM + c * 1024 + p4);
    xv[c][0] = t4.x; xv[c][1] = t4.y; xv[c][2] = t4.z; xv[c][3] = t4.w;
  }
  float o4[3][4];
#pragma unroll
  for (int r = 0; r < 4; ++r){
    float gch[3];
#pragma unroll
    for (int c = 0; c < 3; ++c){
      float tt = b2[c];
#pragma unroll
      for (int o = 0; o < 12; ++o) tt += W2[c * 12 + o] * acc[o][r];
      float inv = g2[c] * rsqrtf(v2[c] + EPSV);
      gch[c] = tt * inv + (bb2[c] - m2[c] * inv) + xv[c][r];
    }
    float f1[3];
#pragma unroll
    for (int c = 0; c < 3; ++c){
      float tt = b3[c] + W3[c*3+0]*gch[0] + W3[c*3+1]*gch[1] + W3[c*3+2]*gch[2];
      float inv = g3[c] * rsqrtf(v3[c] + EPSV);
      float vv = tt * inv + (bb3[c] - m3[c] * inv);
      f1[c] = fmaxf(vv, 0.f);
    }
#pragma unroll
    for (int c = 0; c < 3; ++c){
      float tt = b4[c] + W4[c*3+0]*f1[0] + W4[c*3+1]*f1[1] + W4[c*3+2]*f1[2];
      float inv = g4[c] * rsqrtf(v4[c] + EPSV);
      o4[c][r] = tt * inv + (bb4[c] - m4[c] * inv) + gch[c];
    }
  }
#pragma unroll
  for (int c = 0; c < 3; ++c)
    *(float4*)(out + (size_t)n * FDIM + c * 1024 + p4) =
        make_float4(o4[c][0], o4[c][1], o4[c][2], o4[c][3]);
}

extern "C" void kernel_launch(void* const* d_in, const int* in_sizes, int n_in,
                              void* d_out, int out_size, void* d_ws, size_t ws_size,
                              hipStream_t stream){
  (void)in_sizes; (void)n_in; (void)out_size; (void)ws_size;
  const float* x     = (const float*)d_in[0];
  const int*   ei    = (const int*)d_in[1];
  const float* fc1_W = (const float*)d_in[2];
  const float* fc1_b = (const float*)d_in[3];
  const float* bn1_g = (const float*)d_in[4];
  const float* bn1_b = (const float*)d_in[5];
  const float* bn1_m = (const float*)d_in[6];
  const float* bn1_v = (const float*)d_in[7];
  const float* Wl    = (const float*)d_in[8];
  const float* bl    = (const float*)d_in[9];
  const float* Wr    = (const float*)d_in[10];
  const float* br    = (const float*)d_in[11];
  const float* att   = (const float*)d_in[12];
  const float* gat_b = (const float*)d_in[13];
  const float* fc2_W = (const float*)d_in[14];
  const float* fc2_b = (const float*)d_in[15];
  const float* bn2_g = (const float*)d_in[16];
  const float* bn2_b = (const float*)d_in[17];
  const float* bn2_m = (const float*)d_in[18];
  const float* bn2_v = (const float*)d_in[19];
  const float* ffn1_W= (const float*)d_in[20];
  const float* ffn1_b= (const float*)d_in[21];
  const float* bnf1_g= (const float*)d_in[22];
  const float* bnf1_b= (const float*)d_in[23];
  const float* bnf1_m= (const float*)d_in[24];
  const float* bnf1_v= (const float*)d_in[25];
  const float* ffn2_W= (const float*)d_in[26];
  const float* ffn2_b= (const float*)d_in[27];
  const float* bnf2_g= (const float*)d_in[28];
  const float* bnf2_b= (const float*)d_in[29];
  const float* bnf2_m= (const float*)d_in[30];
  const float* bnf2_v= (const float*)d_in[31];

  char* w = (char*)d_ws;
  u16*   hf     = (u16*)(w);                    // 3,145,728
  u16*   xl     = (u16*)(w + 3145728);          // 12,582,912
  u16*   xr     = (u16*)(w + 15728640);         // 12,582,912
  float* alpha  = (float*)(w + 28385280);       // 73,728 (fallback only)
  int*   cnt    = (int*)(w + 28459008);         // 2048
  int*   offp   = (int*)(w + 28461056);         // 2048
  int*   elist  = (int*)(w + 28465152);         // 18,432

  k_pre<<<2049, 256, 0, stream>>>(x, fc1_W, fc1_b, bn1_g, bn1_b, bn1_m, bn1_v,
                                  hf, ei, cnt, offp, elist);
  k_gemm<<<768, 256, 0, stream>>>(hf, Wl, bl, Wr, br, xl, xr);
  k_post<<<512, 256, 0, stream>>>(ei, cnt, offp, elist, xl, xr, att, alpha,
                                  gat_b,
                                  fc2_W, fc2_b, bn2_g, bn2_b, bn2_m, bn2_v,
                                  ffn1_W, ffn1_b, bnf1_g, bnf1_b, bnf1_m, bnf1_v,
                                  ffn2_W, ffn2_b, bnf2_g, bnf2_b, bnf2_m, bnf2_v,
                                  x, (float*)d_out);
}